// Round 9
// baseline (285.225 us; speedup 1.0000x reference)
//
#include <hip/hip_runtime.h>
#include <hip/hip_bf16.h>
#include <cstdint>
#include <cstddef>

// MXAttention: B=4, S=1024, E=1024, H=16, D=64. fp32 in/out.
// MX quant: blocks of 32 along last/contraction dim, scale=2^(floor(log2(amax))-8),
// e4m3 grid == OCP e4m3fn. qdq = pre-clamp to +-448 then HW v_cvt_pk_fp8_f32 /
// v_cvt_f32_fp8 (RNE). Pre-clamp+convert == reference round-then-clip.
//
// GEMMs: quantized operands are e4m3 x pow2 => exactly bf16 => bf16 MFMA, fp32 acc.
// Q/K/V GEMM epilogues emit results pre-split into bf16 hi+lo planes (Q pre-scaled
// by 0.125, exact); attention uses 3 cross-term MFMAs (lo*lo dropped, ~2^-16).
// V planes stored transposed (Vt[b,h,d,s]). K/V staged via global_load_lds.
// Attention: KT=32 kv-tiles (LDS 25600 B -> 4 WG/CU, grid-limited), score softmax
// in log2-domain (log2e folded into the dequant scale; exp2f), P hi/lo split via
// packed bf16 converts. XCD-swizzled block mapping clusters a head's q-tiles.
//
// ws layout (bytes):
//   [ 0, 8)MB  XQb  bf16 quantized input; later reused as CTXQb
//   [ 8,16)MB  WQb/WKb/WVb/WOb (2 MB each)
//   [16,24) Qhi [24,32) Qlo   [32,40) Khi [40,48) Klo   [48,56) Vthi [56,64) Vtlo

#define S_LEN 1024
#define E_DIM 1024
#define NH    16
#define DH    64
#define BATCH 4
#define NROWS (BATCH * S_LEN)  // 4096

typedef short          bf16x8  __attribute__((ext_vector_type(8)));
typedef float          f32x4   __attribute__((ext_vector_type(4)));
typedef unsigned short u16x8   __attribute__((ext_vector_type(8)));
typedef unsigned short u16x4   __attribute__((ext_vector_type(4)));

// ---------------- MX quant helpers ----------------

// scale = 2^(clamp(floor(log2(amax))-8, -126, 126)), 1.0 if amax==0.
__device__ __forceinline__ void mx_scale_bits(float amax, float& scale, float& inv) {
  int eb = (int)(__float_as_uint(amax) >> 23);  // biased exponent
  int sb = eb - 8;
  sb = sb < 1 ? 1 : (sb > 253 ? 253 : sb);
  float sc = __uint_as_float((unsigned)sb << 23);
  float iv = __uint_as_float((unsigned)(254 - sb) << 23);
  bool nz = (amax > 0.0f);
  scale = nz ? sc : 1.0f;
  inv   = nz ? iv : 1.0f;
}

// round a,b to the e4m3fn grid: pre-clamp +-448 (== ref round-then-clip), HW RNE cvt.
__device__ __forceinline__ void qdq2(float& a, float& b) {
  a = fminf(fmaxf(a, -448.0f), 448.0f);
  b = fminf(fmaxf(b, -448.0f), 448.0f);
  int p = __builtin_amdgcn_cvt_pk_fp8_f32(a, b, 0, false);
  a = __builtin_amdgcn_cvt_f32_fp8(p, 0);
  b = __builtin_amdgcn_cvt_f32_fp8(p, 1);
}

__device__ __forceinline__ unsigned short f32_to_bf16_rne(float f) {
  unsigned u = __float_as_uint(f);
  unsigned r = 0x7FFFu + ((u >> 16) & 1u);
  return (unsigned short)((u + r) >> 16);
}

// ---------------- quant kernel: fp32 in -> bf16 out (exact) ----------------

__device__ __forceinline__ void mxq_body(const float* __restrict__ in,
                                         unsigned short* __restrict__ out, int b) {
  const float4* p = (const float4*)(in + (size_t)b * 32);
  float v[32];
#pragma unroll
  for (int g = 0; g < 8; ++g) {
    float4 t = p[g];
    v[g * 4 + 0] = t.x; v[g * 4 + 1] = t.y; v[g * 4 + 2] = t.z; v[g * 4 + 3] = t.w;
  }
  float amax = 0.0f;
#pragma unroll
  for (int i = 0; i < 32; ++i) amax = fmaxf(amax, __builtin_fabsf(v[i]));
  float scale, inv;
  mx_scale_bits(amax, scale, inv);
  u16x8* q = (u16x8*)(out + (size_t)b * 32);
#pragma unroll
  for (int g = 0; g < 4; ++g) {
    u16x8 o;
#pragma unroll
    for (int e = 0; e < 8; e += 2) {
      float a = v[g * 8 + e] * inv, c = v[g * 8 + e + 1] * inv;
      qdq2(a, c);
      o[e]     = (unsigned short)(__float_as_uint(a * scale) >> 16);  // exact bf16
      o[e + 1] = (unsigned short)(__float_as_uint(c * scale) >> 16);
    }
    q[g] = o;
  }
}

// one launch quantizes x (blocks 0..511) + 4 weights (128 blocks each)
__global__ __launch_bounds__(256)
void mxq_all(const float* __restrict__ x,
             const float* __restrict__ w0, const float* __restrict__ w1,
             const float* __restrict__ w2, const float* __restrict__ w3,
             unsigned short* __restrict__ ox,
             unsigned short* __restrict__ o0, unsigned short* __restrict__ o1,
             unsigned short* __restrict__ o2, unsigned short* __restrict__ o3) {
  int blk = blockIdx.x;
  const float* in;
  unsigned short* out;
  int base;
  if (blk < 512)      { in = x;  out = ox; base = blk; }
  else if (blk < 640) { in = w0; out = o0; base = blk - 512; }
  else if (blk < 768) { in = w1; out = o1; base = blk - 640; }
  else if (blk < 896) { in = w2; out = o2; base = blk - 768; }
  else                { in = w3; out = o3; base = blk - 896; }
  mxq_body(in, out, base * 256 + threadIdx.x);
}

// ---------------- fused Q/K/V bf16 MFMA NT GEMM ----------------
// grid (8, 32, 3): z selects weight/bias/output. 128x128 tile, BK=64, 4 waves.
// z=0: Q hi/lo planes pre-scaled 0.125. z=1: K hi/lo planes. z=2: Vt hi/lo planes.

__global__ __launch_bounds__(256)
void gemm_qkv(const unsigned short* __restrict__ XQ,
              const unsigned short* __restrict__ Wqw, const unsigned short* __restrict__ Wkw,
              const unsigned short* __restrict__ Wvw,
              const float* __restrict__ bq, const float* __restrict__ bk,
              const float* __restrict__ bv,
              unsigned short* __restrict__ Qhi, unsigned short* __restrict__ Qlo,
              unsigned short* __restrict__ Khi, unsigned short* __restrict__ Klo,
              unsigned short* __restrict__ Vthi, unsigned short* __restrict__ Vtlo) {
  const int z = blockIdx.z;
  const unsigned short* Bw = (z == 0) ? Wqw : (z == 1) ? Wkw : Wvw;
  const float* bias = (z == 0) ? bq : (z == 1) ? bk : bv;
  unsigned short* Phi = (z == 0) ? Qhi : (z == 1) ? Khi : Vthi;
  unsigned short* Plo = (z == 0) ? Qlo : (z == 1) ? Klo : Vtlo;
  const float pre = (z == 0) ? 0.125f : 1.0f;

  __shared__ unsigned short sA[128 * 64];
  __shared__ unsigned short sB[128 * 64];
  const int tid = threadIdx.x;
  const int w = tid >> 6, ln = tid & 63;
  const int bm = blockIdx.y * 128, bn = blockIdx.x * 128;
  const int wm = (w >> 1) * 64, wn = (w & 1) * 64;
  const int quad = ln >> 4, col = ln & 15;

  f32x4 acc[4][4];
  f32x4 zero = {0.0f, 0.0f, 0.0f, 0.0f};
#pragma unroll
  for (int i = 0; i < 4; ++i)
#pragma unroll
    for (int j = 0; j < 4; ++j) acc[i][j] = zero;

  const int srow = ln >> 3;
  const int gsw  = (ln & 7) ^ srow;
  const int xo0 = (quad ^ (ln & 7)) * 8;
  const int xo1 = ((quad ^ 4) ^ (ln & 7)) * 8;

  for (int k0 = 0; k0 < 1024; k0 += 64) {
    __syncthreads();
#pragma unroll
    for (int q = 0; q < 4; ++q) {
      int row = w * 32 + q * 8 + srow;
      const unsigned short* ga = XQ + (size_t)(bm + row) * 1024 + k0 + gsw * 8;
      const unsigned short* gb = Bw + (size_t)(bn + row) * 1024 + k0 + gsw * 8;
      __builtin_amdgcn_global_load_lds(
          (const __attribute__((address_space(1))) unsigned int*)ga,
          (__attribute__((address_space(3))) unsigned int*)(sA + (w * 32 + q * 8) * 64),
          16, 0, 0);
      __builtin_amdgcn_global_load_lds(
          (const __attribute__((address_space(1))) unsigned int*)gb,
          (__attribute__((address_space(3))) unsigned int*)(sB + (w * 32 + q * 8) * 64),
          16, 0, 0);
    }
    __syncthreads();

#pragma unroll
    for (int ks = 0; ks < 2; ++ks) {
      const int xo = ks ? xo1 : xo0;
      bf16x8 af[4], bf[4];
#pragma unroll
      for (int t = 0; t < 4; ++t) {
        af[t] = *(const bf16x8*)(sA + (wm + t * 16 + col) * 64 + xo);
        bf[t] = *(const bf16x8*)(sB + (wn + t * 16 + col) * 64 + xo);
      }
#pragma unroll
      for (int ti = 0; ti < 4; ++ti)
#pragma unroll
        for (int tj = 0; tj < 4; ++tj)
          acc[ti][tj] = __builtin_amdgcn_mfma_f32_16x16x32_bf16(af[ti], bf[tj], acc[ti][tj], 0, 0, 0);
    }
  }

#pragma unroll
  for (int ti = 0; ti < 4; ++ti) {
#pragma unroll
    for (int tj = 0; tj < 4; ++tj) {
      int n = bn + wn + tj * 16 + col;
      float bv_ = bias[n];
      if (z != 2) {
#pragma unroll
        for (int i = 0; i < 4; ++i) {
          int m = bm + wm + ti * 16 + quad * 4 + i;
          float v = (acc[ti][tj][i] + bv_) * pre;
          unsigned short h = f32_to_bf16_rne(v);
          float hf = __uint_as_float((unsigned)h << 16);
          Phi[(size_t)m * 1024 + n] = h;
          Plo[(size_t)m * 1024 + n] = f32_to_bf16_rne(v - hf);
        }
      } else {
        int m0 = bm + wm + ti * 16 + quad * 4;  // 4 consecutive s in one batch
        u16x4 h4, l4;
#pragma unroll
        for (int i = 0; i < 4; ++i) {
          float v = acc[ti][tj][i] + bv_;
          unsigned short h = f32_to_bf16_rne(v);
          float hf = __uint_as_float((unsigned)h << 16);
          h4[i] = h;
          l4[i] = f32_to_bf16_rne(v - hf);
        }
        size_t idx = ((size_t)((m0 >> 10) * 1024 + n)) * 1024 + (m0 & 1023);
        *(u16x4*)(Phi + idx) = h4;
        *(u16x4*)(Plo + idx) = l4;
      }
    }
  }
}

// ---------------- O-projection GEMM: 64x128 tile (512 WGs, 2/CU) ----------------

__global__ __launch_bounds__(256)
void gemm_o(const unsigned short* __restrict__ A, const unsigned short* __restrict__ Bw,
            const float* __restrict__ bias, float* __restrict__ C) {
  __shared__ unsigned short sA[64 * 64];
  __shared__ unsigned short sB[128 * 64];
  const int tid = threadIdx.x;
  const int w = tid >> 6, ln = tid & 63;
  const int bm = blockIdx.y * 64, bn = blockIdx.x * 128;
  const int wr = (w >> 1) * 32, wc = (w & 1) * 64;
  const int quad = ln >> 4, col = ln & 15;

  f32x4 acc[2][4];
  f32x4 zero = {0.0f, 0.0f, 0.0f, 0.0f};
#pragma unroll
  for (int i = 0; i < 2; ++i)
#pragma unroll
    for (int j = 0; j < 4; ++j) acc[i][j] = zero;

  const int srow = ln >> 3;
  const int gsw  = (ln & 7) ^ srow;
  const int xo0 = (quad ^ (ln & 7)) * 8;
  const int xo1 = ((quad ^ 4) ^ (ln & 7)) * 8;

  for (int k0 = 0; k0 < 1024; k0 += 64) {
    __syncthreads();
#pragma unroll
    for (int qa = 0; qa < 2; ++qa) {
      int row = w * 16 + qa * 8 + srow;
      __builtin_amdgcn_global_load_lds(
          (const __attribute__((address_space(1))) unsigned int*)(A + (size_t)(bm + row) * 1024 + k0 + gsw * 8),
          (__attribute__((address_space(3))) unsigned int*)(sA + (w * 16 + qa * 8) * 64),
          16, 0, 0);
    }
#pragma unroll
    for (int qb = 0; qb < 4; ++qb) {
      int row = w * 32 + qb * 8 + srow;
      __builtin_amdgcn_global_load_lds(
          (const __attribute__((address_space(1))) unsigned int*)(Bw + (size_t)(bn + row) * 1024 + k0 + gsw * 8),
          (__attribute__((address_space(3))) unsigned int*)(sB + (w * 32 + qb * 8) * 64),
          16, 0, 0);
    }
    __syncthreads();

#pragma unroll
    for (int ks = 0; ks < 2; ++ks) {
      const int xo = ks ? xo1 : xo0;
      bf16x8 af[2], bf[4];
#pragma unroll
      for (int t = 0; t < 2; ++t)
        af[t] = *(const bf16x8*)(sA + (wr + t * 16 + col) * 64 + xo);
#pragma unroll
      for (int t = 0; t < 4; ++t)
        bf[t] = *(const bf16x8*)(sB + (wc + t * 16 + col) * 64 + xo);
#pragma unroll
      for (int ti = 0; ti < 2; ++ti)
#pragma unroll
        for (int tj = 0; tj < 4; ++tj)
          acc[ti][tj] = __builtin_amdgcn_mfma_f32_16x16x32_bf16(af[ti], bf[tj], acc[ti][tj], 0, 0, 0);
    }
  }

#pragma unroll
  for (int ti = 0; ti < 2; ++ti) {
#pragma unroll
    for (int tj = 0; tj < 4; ++tj) {
      int n = bn + wc + tj * 16 + col;
      float bv_ = bias[n];
#pragma unroll
      for (int i = 0; i < 4; ++i) {
        int m = bm + wr + ti * 16 + quad * 4 + i;
        C[(size_t)m * 1024 + n] = acc[ti][tj][i] + bv_;
      }
    }
  }
}

// ---------------- MFMA flash attention, fused score+ctx MX quant ----------
// grid (16,64), XCD-swizzled: id=128a+8b+c -> qt=b, bh=8a+c (a head's 16 q-tiles
// share one XCD's L2). 64 q-rows/WG, kv tiles of 32, 4 waves x 16 q-rows.
// LDS: Khi/Klo 32x64, Vthi/Vtlo 64x32 (chunk-XOR swizzled), P 16x36 u32/wave.
// Softmax in log2 domain: log2e folded into dequant scale, exp2f for p/alpha.

__global__ __launch_bounds__(256, 4)
void attn_kernel(const unsigned short* __restrict__ Qhi, const unsigned short* __restrict__ Qlo,
                 const unsigned short* __restrict__ Khi, const unsigned short* __restrict__ Klo,
                 const unsigned short* __restrict__ Vthi, const unsigned short* __restrict__ Vtlo,
                 unsigned short* __restrict__ ctxq) {
  const int tid = threadIdx.x;
  const int id = blockIdx.y * 16 + blockIdx.x;
  const int qt = (id >> 3) & 15;
  const int bh = ((id >> 7) << 3) | (id & 7);
  const int b = bh >> 4, h = bh & 15;
  const int w = tid >> 6, ln = tid & 63, quad = ln >> 4, col = ln & 15;

  __shared__ __align__(16) char smem[25600];
  short* sK = (short*)smem;  // Khi@0, Klo@4096B, Vthi@8192B, Vtlo@12288B
  unsigned int* Pw = (unsigned int*)(smem + 16384) + w * 576;  // 16 x 36 u32 per wave

  // Q fragments straight from global hi/lo planes (pre-scaled by 1/8)
  bf16x8 qh[2], ql[2];
  {
    const size_t qoff = (size_t)(b * 1024 + qt * 64 + w * 16 + col) * 1024 + h * 64 + quad * 8;
    qh[0] = *(const bf16x8*)(Qhi + qoff);
    qh[1] = *(const bf16x8*)(Qhi + qoff + 32);
    ql[0] = *(const bf16x8*)(Qlo + qoff);
    ql[1] = *(const bf16x8*)(Qlo + qoff + 32);
  }

  // staging: wave w stages plane w; K planes: 32 kv-rows x 64 d; V planes: 64 d-rows x 32 kv
  const unsigned short* gplane = (w == 0) ? Khi : (w == 1) ? Klo : (w == 2) ? Vthi : Vtlo;
  short* splane = sK + w * 2048;
  const int r8 = ln >> 3, ch = (ln & 7) ^ r8;
  const int rv = ln >> 2, cv = (ln & 3) ^ (rv & 3);
  const unsigned short* bp = (w < 2)
      ? gplane + (size_t)(b * 1024 + r8) * 1024 + h * 64 + ch * 8
      : gplane + (size_t)(b * 1024 + h * 64 + rv) * 1024 + cv * 8;
  const size_t gstep = (w < 2) ? 8192 : 16384;
  const int ktstep = (w < 2) ? 32768 : 32;

  // fragment-read chunk offsets (u16 units)
  const int cx0 = (quad ^ (col & 7)) * 8;
  const int cx1 = ((quad + 4) ^ (col & 7)) * 8;
  const int cvv = (quad ^ (col & 3)) * 8;

  f32x4 o[4];
  f32x4 zero = {0.0f, 0.0f, 0.0f, 0.0f};
#pragma unroll
  for (int t = 0; t < 4; ++t) o[t] = zero;
  float m_[4], l_[4];
#pragma unroll
  for (int i = 0; i < 4; ++i) { m_[i] = -3.0e38f; l_[i] = 0.0f; }

  const float LOG2E = 1.44269504088896340736f;

#pragma unroll 1
  for (int kt = 0; kt < 32; ++kt) {
    __syncthreads();  // prior tile's fragment reads complete before restaging
#pragma unroll
    for (int g = 0; g < 4; ++g) {
      __builtin_amdgcn_global_load_lds(
          (const __attribute__((address_space(1))) unsigned int*)(bp + g * gstep),
          (__attribute__((address_space(3))) unsigned int*)(splane + g * 512),
          16, 0, 0);
    }
    bp += ktstep;
    __syncthreads();  // staging visible

    // S = (Qhi+Qlo)·(Khi+Klo)^T, 3 cross terms; t in {0,1} kv-frags
    f32x4 s0 = zero, s1 = zero;
#pragma unroll
    for (int ks = 0; ks < 2; ++ks) {
      const int xo = ks ? cx1 : cx0;
      bf16x8 kh = *(const bf16x8*)(sK + col * 64 + xo);
      bf16x8 kl = *(const bf16x8*)(sK + 2048 + col * 64 + xo);
      s0 = __builtin_amdgcn_mfma_f32_16x16x32_bf16(ql[ks], kh, s0, 0, 0, 0);
      s0 = __builtin_amdgcn_mfma_f32_16x16x32_bf16(qh[ks], kl, s0, 0, 0, 0);
      s0 = __builtin_amdgcn_mfma_f32_16x16x32_bf16(qh[ks], kh, s0, 0, 0, 0);
      kh = *(const bf16x8*)(sK + (16 + col) * 64 + xo);
      kl = *(const bf16x8*)(sK + 2048 + (16 + col) * 64 + xo);
      s1 = __builtin_amdgcn_mfma_f32_16x16x32_bf16(ql[ks], kh, s1, 0, 0, 0);
      s1 = __builtin_amdgcn_mfma_f32_16x16x32_bf16(qh[ks], kl, s1, 0, 0, 0);
      s1 = __builtin_amdgcn_mfma_f32_16x16x32_bf16(qh[ks], kh, s1, 0, 0, 0);
    }

    // MX quantize scores: the 32-kv tile is exactly one MX block per q-row
    float am[4];
#pragma unroll
    for (int i = 0; i < 4; ++i)
      am[i] = fmaxf(__builtin_fabsf(s0[i]), __builtin_fabsf(s1[i]));
#pragma unroll
    for (int msk = 1; msk <= 8; msk <<= 1)
#pragma unroll
      for (int i = 0; i < 4; ++i) am[i] = fmaxf(am[i], __shfl_xor(am[i], msk, 64));
    float mt[4];
#pragma unroll
    for (int i = 0; i < 4; ++i) {
      float sc, iv;
      mx_scale_bits(am[i], sc, iv);
      float scl = sc * LOG2E;  // fold dequant scale + log2e (1-ulp inside exp)
      float q0 = s0[i] * iv, q1 = s1[i] * iv;
      qdq2(q0, q1);
      q0 *= scl; q1 *= scl;
      s0[i] = q0; s1[i] = q1;
      mt[i] = fmaxf(q0, q1);
    }
#pragma unroll
    for (int msk = 1; msk <= 8; msk <<= 1)
#pragma unroll
      for (int i = 0; i < 4; ++i) mt[i] = fmaxf(mt[i], __shfl_xor(mt[i], msk, 64));

    // online softmax (log2 domain)
#pragma unroll
    for (int i = 0; i < 4; ++i) {
      float mnew  = fmaxf(m_[i], mt[i]);
      float alpha = exp2f(m_[i] - mnew);
      m_[i] = mnew;
      l_[i] *= alpha;
#pragma unroll
      for (int t = 0; t < 4; ++t) o[t][i] *= alpha;
      float p0 = exp2f(s0[i] - mnew);
      float p1 = exp2f(s1[i] - mnew);
      s0[i] = p0; s1[i] = p1;
      l_[i] += p0 + p1;
    }

    // P: C-layout -> wave-private LDS (hi/lo packed u32, stride 36) -> A-frags
#pragma unroll
    for (int i = 0; i < 4; ++i) {
      float a = s0[i], c = s1[i];
      __hip_bfloat162 h2 = __float22bfloat162_rn(make_float2(a, c));
      unsigned uh = *(unsigned*)&h2;                 // hi16 = c_hi, lo16 = a_hi
      float af = __uint_as_float(uh << 16);
      float cf = __uint_as_float(uh & 0xffff0000u);
      __hip_bfloat162 l2 = __float22bfloat162_rn(make_float2(a - af, c - cf));
      unsigned ul = *(unsigned*)&l2;
      Pw[(quad * 4 + i) * 36 + col]      = (uh << 16) | (ul & 0xffffu);
      Pw[(quad * 4 + i) * 36 + 16 + col] = (uh & 0xffff0000u) | (ul >> 16);
    }
    bf16x8 pah, pal;
    {
      const unsigned int* pr = Pw + col * 36 + quad * 8;
      uint4 u0 = *(const uint4*)pr;
      uint4 u1 = *(const uint4*)(pr + 4);
      unsigned int uu[8] = {u0.x, u0.y, u0.z, u0.w, u1.x, u1.y, u1.z, u1.w};
#pragma unroll
      for (int e = 0; e < 8; ++e) {
        pah[e] = (short)(uu[e] >> 16);
        pal[e] = (short)(uu[e] & 0xffffu);
      }
    }

    // O += (Phi+Plo)·(Vhi+Vlo), 3 cross terms (K-dim = 32 -> single A-frag)
#pragma unroll
    for (int nt = 0; nt < 4; ++nt) {
      const int rb = (nt * 16 + col) * 32;
      bf16x8 vh = *(const bf16x8*)(sK + 4096 + rb + cvv);
      bf16x8 vl = *(const bf16x8*)(sK + 6144 + rb + cvv);
      o[nt] = __builtin_amdgcn_mfma_f32_16x16x32_bf16(pal, vh, o[nt], 0, 0, 0);
      o[nt] = __builtin_amdgcn_mfma_f32_16x16x32_bf16(pah, vl, o[nt], 0, 0, 0);
      o[nt] = __builtin_amdgcn_mfma_f32_16x16x32_bf16(pah, vh, o[nt], 0, 0, 0);
    }
  }

  // normalize + fused ctx MX quant (blocks of 32 along E = frag pairs) -> bf16
#pragma unroll
  for (int msk = 1; msk <= 8; msk <<= 1)
#pragma unroll
    for (int i = 0; i < 4; ++i) l_[i] += __shfl_xor(l_[i], msk, 64);
  float cam0[4], cam1[4];
#pragma unroll
  for (int i = 0; i < 4; ++i) {
    float invl = 1.0f / l_[i];
#pragma unroll
    for (int t = 0; t < 4; ++t) o[t][i] *= invl;
    cam0[i] = fmaxf(__builtin_fabsf(o[0][i]), __builtin_fabsf(o[1][i]));
    cam1[i] = fmaxf(__builtin_fabsf(o[2][i]), __builtin_fabsf(o[3][i]));
  }
#pragma unroll
  for (int msk = 1; msk <= 8; msk <<= 1)
#pragma unroll
    for (int i = 0; i < 4; ++i) {
      cam0[i] = fmaxf(cam0[i], __shfl_xor(cam0[i], msk, 64));
      cam1[i] = fmaxf(cam1[i], __shfl_xor(cam1[i], msk, 64));
    }
#pragma unroll
  for (int i = 0; i < 4; ++i) {
    float sc0, iv0, sc1, iv1;
    mx_scale_bits(cam0[i], sc0, iv0);
    mx_scale_bits(cam1[i], sc1, iv1);
    float q0 = o[0][i] * iv0, q1 = o[1][i] * iv0;
    float q2 = o[2][i] * iv1, q3 = o[3][i] * iv1;
    qdq2(q0, q1);
    qdq2(q2, q3);
    q0 *= sc0; q1 *= sc0; q2 *= sc1; q3 *= sc1;
    int rowg = b * 1024 + qt * 64 + w * 16 + quad * 4 + i;
    size_t base = (size_t)rowg * 1024 + h * 64 + col;
    ctxq[base +  0] = (unsigned short)(__float_as_uint(q0) >> 16);
    ctxq[base + 16] = (unsigned short)(__float_as_uint(q1) >> 16);
    ctxq[base + 32] = (unsigned short)(__float_as_uint(q2) >> 16);
    ctxq[base + 48] = (unsigned short)(__float_as_uint(q3) >> 16);
  }
}

// ---------------- launch ----------------

extern "C" void kernel_launch(void* const* d_in, const int* in_sizes, int n_in,
                              void* d_out, int out_size, void* d_ws, size_t ws_size,
                              hipStream_t stream) {
  (void)in_sizes; (void)n_in; (void)out_size; (void)ws_size;
  const float* x  = (const float*)d_in[0];
  const float* Wq = (const float*)d_in[1];
  const float* bq = (const float*)d_in[2];
  const float* Wk = (const float*)d_in[3];
  const float* bk = (const float*)d_in[4];
  const float* Wv = (const float*)d_in[5];
  const float* bv = (const float*)d_in[6];
  const float* Wo = (const float*)d_in[7];
  const float* bo = (const float*)d_in[8];

  char* wsb = (char*)d_ws;
  const size_t MB = (size_t)1 << 20;
  unsigned short* XQb   = (unsigned short*)(wsb + 0);
  unsigned short* WQb   = (unsigned short*)(wsb + 8 * MB);
  unsigned short* WKb   = (unsigned short*)(wsb + 10 * MB);
  unsigned short* WVb   = (unsigned short*)(wsb + 12 * MB);
  unsigned short* WOb   = (unsigned short*)(wsb + 14 * MB);
  unsigned short* Qhi   = (unsigned short*)(wsb + 16 * MB);
  unsigned short* Qlo   = (unsigned short*)(wsb + 24 * MB);
  unsigned short* Khi   = (unsigned short*)(wsb + 32 * MB);
  unsigned short* Klo   = (unsigned short*)(wsb + 40 * MB);
  unsigned short* Vthi  = (unsigned short*)(wsb + 48 * MB);
  unsigned short* Vtlo  = (unsigned short*)(wsb + 56 * MB);
  unsigned short* CTXQb = XQb;  // reuse: XQ dead after V projection

  mxq_all<<<1024, 256, 0, stream>>>(x, Wq, Wk, Wv, Wo, XQb, WQb, WKb, WVb, WOb);

  dim3 qkvgrid(E_DIM / 128, NROWS / 128, 3);  // (8, 32, 3) = 768 WGs
  gemm_qkv<<<qkvgrid, 256, 0, stream>>>(XQb, WQb, WKb, WVb, bq, bk, bv,
                                        Qhi, Qlo, Khi, Klo, Vthi, Vtlo);

  dim3 agrid(16, 64);  // 1024 WGs, XCD-swizzled inside the kernel
  attn_kernel<<<agrid, 256, 0, stream>>>(Qhi, Qlo, Khi, Klo, Vthi, Vtlo, CTXQb);

  dim3 ogrid(E_DIM / 128, NROWS / 64);  // (8, 64) = 512 WGs
  gemm_o<<<ogrid, 256, 0, stream>>>(CTXQb, WOb, bo, (float*)d_out);
}

// Round 10
// 277.076 us; speedup vs baseline: 1.0294x; 1.0294x over previous
//
#include <hip/hip_runtime.h>
#include <hip/hip_bf16.h>
#include <cstdint>
#include <cstddef>

// MXAttention: B=4, S=1024, E=1024, H=16, D=64. fp32 in/out.
// MX quant: blocks of 32 along last/contraction dim, scale=2^(floor(log2(amax))-8),
// e4m3 grid == OCP e4m3fn. qdq = pre-clamp to +-448 then HW v_cvt_pk_fp8_f32 /
// v_cvt_f32_fp8 (RNE). Pre-clamp+convert == reference round-then-clip.
//
// GEMMs: quantized operands are e4m3 x pow2 => exactly bf16 => bf16 MFMA, fp32 acc.
// Q/K/V GEMM epilogues emit results pre-split into bf16 hi+lo planes (Q pre-scaled
// by 0.125, exact); attention uses 3 cross-term MFMAs (lo*lo dropped, ~2^-16).
// V planes stored transposed (Vt[b,h,d,s]). K/V staged via global_load_lds.
// Attention: KT=64 kv-tiles (R8 structure), ONE reduction phase per tile
// (qdq monotone => row-max of quantized = dequant(qdq(signed max))), DPP 16-lane
// butterflies instead of ds_swizzle, log2-domain softmax, XCD-swizzled grid.
//
// ws layout (bytes):
//   [ 0, 8)MB  XQb  bf16 quantized input; later reused as CTXQb
//   [ 8,16)MB  WQb/WKb/WVb/WOb (2 MB each)
//   [16,24) Qhi [24,32) Qlo   [32,40) Khi [40,48) Klo   [48,56) Vthi [56,64) Vtlo

#define S_LEN 1024
#define E_DIM 1024
#define NH    16
#define DH    64
#define BATCH 4
#define NROWS (BATCH * S_LEN)  // 4096

typedef short          bf16x8  __attribute__((ext_vector_type(8)));
typedef float          f32x4   __attribute__((ext_vector_type(4)));
typedef unsigned short u16x8   __attribute__((ext_vector_type(8)));
typedef unsigned short u16x4   __attribute__((ext_vector_type(4)));

// ---------------- MX quant helpers ----------------

// scale = 2^(clamp(floor(log2(amax))-8, -126, 126)), 1.0 if amax==0.
__device__ __forceinline__ void mx_scale_bits(float amax, float& scale, float& inv) {
  int eb = (int)(__float_as_uint(amax) >> 23);  // biased exponent
  int sb = eb - 8;
  sb = sb < 1 ? 1 : (sb > 253 ? 253 : sb);
  float sc = __uint_as_float((unsigned)sb << 23);
  float iv = __uint_as_float((unsigned)(254 - sb) << 23);
  bool nz = (amax > 0.0f);
  scale = nz ? sc : 1.0f;
  inv   = nz ? iv : 1.0f;
}

// round a,b to the e4m3fn grid: pre-clamp +-448 (== ref round-then-clip), HW RNE cvt.
__device__ __forceinline__ void qdq2(float& a, float& b) {
  a = fminf(fmaxf(a, -448.0f), 448.0f);
  b = fminf(fmaxf(b, -448.0f), 448.0f);
  int p = __builtin_amdgcn_cvt_pk_fp8_f32(a, b, 0, false);
  a = __builtin_amdgcn_cvt_f32_fp8(p, 0);
  b = __builtin_amdgcn_cvt_f32_fp8(p, 1);
}

__device__ __forceinline__ unsigned short f32_to_bf16_rne(float f) {
  unsigned u = __float_as_uint(f);
  unsigned r = 0x7FFFu + ((u >> 16) & 1u);
  return (unsigned short)((u + r) >> 16);
}

// ---- DPP 16-lane butterflies (quad_perm xor1=0xB1, xor2=0x4E, row_ror:4/8) ----
__device__ __forceinline__ float dpp_bf(float x, const int ctrl_unused) { return x; }

#define DPP_STEP(x, ctrl, OP)                                                        \
  x = OP(x, __uint_as_float(__builtin_amdgcn_mov_dpp(__float_as_uint(x), ctrl, 0xF, 0xF, false)))

__device__ __forceinline__ float dpp_max16(float x) {
  DPP_STEP(x, 0xB1,  fmaxf);
  DPP_STEP(x, 0x4E,  fmaxf);
  DPP_STEP(x, 0x124, fmaxf);
  DPP_STEP(x, 0x128, fmaxf);
  return x;
}
__device__ __forceinline__ float dpp_min16(float x) {
  DPP_STEP(x, 0xB1,  fminf);
  DPP_STEP(x, 0x4E,  fminf);
  DPP_STEP(x, 0x124, fminf);
  DPP_STEP(x, 0x128, fminf);
  return x;
}
__device__ __forceinline__ float dpp_addf(float a, float b) { return a + b; }
__device__ __forceinline__ float dpp_sum16(float x) {
  DPP_STEP(x, 0xB1,  dpp_addf);
  DPP_STEP(x, 0x4E,  dpp_addf);
  DPP_STEP(x, 0x124, dpp_addf);
  DPP_STEP(x, 0x128, dpp_addf);
  return x;
}

// ---------------- quant kernel: fp32 in -> bf16 out (exact) ----------------

__device__ __forceinline__ void mxq_body(const float* __restrict__ in,
                                         unsigned short* __restrict__ out, int b) {
  const float4* p = (const float4*)(in + (size_t)b * 32);
  float v[32];
#pragma unroll
  for (int g = 0; g < 8; ++g) {
    float4 t = p[g];
    v[g * 4 + 0] = t.x; v[g * 4 + 1] = t.y; v[g * 4 + 2] = t.z; v[g * 4 + 3] = t.w;
  }
  float amax = 0.0f;
#pragma unroll
  for (int i = 0; i < 32; ++i) amax = fmaxf(amax, __builtin_fabsf(v[i]));
  float scale, inv;
  mx_scale_bits(amax, scale, inv);
  u16x8* q = (u16x8*)(out + (size_t)b * 32);
#pragma unroll
  for (int g = 0; g < 4; ++g) {
    u16x8 o;
#pragma unroll
    for (int e = 0; e < 8; e += 2) {
      float a = v[g * 8 + e] * inv, c = v[g * 8 + e + 1] * inv;
      qdq2(a, c);
      o[e]     = (unsigned short)(__float_as_uint(a * scale) >> 16);  // exact bf16
      o[e + 1] = (unsigned short)(__float_as_uint(c * scale) >> 16);
    }
    q[g] = o;
  }
}

// one launch quantizes x (blocks 0..511) + 4 weights (128 blocks each)
__global__ __launch_bounds__(256)
void mxq_all(const float* __restrict__ x,
             const float* __restrict__ w0, const float* __restrict__ w1,
             const float* __restrict__ w2, const float* __restrict__ w3,
             unsigned short* __restrict__ ox,
             unsigned short* __restrict__ o0, unsigned short* __restrict__ o1,
             unsigned short* __restrict__ o2, unsigned short* __restrict__ o3) {
  int blk = blockIdx.x;
  const float* in;
  unsigned short* out;
  int base;
  if (blk < 512)      { in = x;  out = ox; base = blk; }
  else if (blk < 640) { in = w0; out = o0; base = blk - 512; }
  else if (blk < 768) { in = w1; out = o1; base = blk - 640; }
  else if (blk < 896) { in = w2; out = o2; base = blk - 768; }
  else                { in = w3; out = o3; base = blk - 896; }
  mxq_body(in, out, base * 256 + threadIdx.x);
}

// ---------------- fused Q/K/V bf16 MFMA NT GEMM ----------------
// grid (8, 32, 3): z selects weight/bias/output. 128x128 tile, BK=64, 4 waves.
// z=0: Q hi/lo planes pre-scaled 0.125. z=1: K hi/lo planes. z=2: Vt hi/lo planes.

__global__ __launch_bounds__(256)
void gemm_qkv(const unsigned short* __restrict__ XQ,
              const unsigned short* __restrict__ Wqw, const unsigned short* __restrict__ Wkw,
              const unsigned short* __restrict__ Wvw,
              const float* __restrict__ bq, const float* __restrict__ bk,
              const float* __restrict__ bv,
              unsigned short* __restrict__ Qhi, unsigned short* __restrict__ Qlo,
              unsigned short* __restrict__ Khi, unsigned short* __restrict__ Klo,
              unsigned short* __restrict__ Vthi, unsigned short* __restrict__ Vtlo) {
  const int z = blockIdx.z;
  const unsigned short* Bw = (z == 0) ? Wqw : (z == 1) ? Wkw : Wvw;
  const float* bias = (z == 0) ? bq : (z == 1) ? bk : bv;
  unsigned short* Phi = (z == 0) ? Qhi : (z == 1) ? Khi : Vthi;
  unsigned short* Plo = (z == 0) ? Qlo : (z == 1) ? Klo : Vtlo;
  const float pre = (z == 0) ? 0.125f : 1.0f;

  __shared__ unsigned short sA[128 * 64];
  __shared__ unsigned short sB[128 * 64];
  const int tid = threadIdx.x;
  const int w = tid >> 6, ln = tid & 63;
  const int bm = blockIdx.y * 128, bn = blockIdx.x * 128;
  const int wm = (w >> 1) * 64, wn = (w & 1) * 64;
  const int quad = ln >> 4, col = ln & 15;

  f32x4 acc[4][4];
  f32x4 zero = {0.0f, 0.0f, 0.0f, 0.0f};
#pragma unroll
  for (int i = 0; i < 4; ++i)
#pragma unroll
    for (int j = 0; j < 4; ++j) acc[i][j] = zero;

  const int srow = ln >> 3;
  const int gsw  = (ln & 7) ^ srow;
  const int xo0 = (quad ^ (ln & 7)) * 8;
  const int xo1 = ((quad ^ 4) ^ (ln & 7)) * 8;

  for (int k0 = 0; k0 < 1024; k0 += 64) {
    __syncthreads();
#pragma unroll
    for (int q = 0; q < 4; ++q) {
      int row = w * 32 + q * 8 + srow;
      const unsigned short* ga = XQ + (size_t)(bm + row) * 1024 + k0 + gsw * 8;
      const unsigned short* gb = Bw + (size_t)(bn + row) * 1024 + k0 + gsw * 8;
      __builtin_amdgcn_global_load_lds(
          (const __attribute__((address_space(1))) unsigned int*)ga,
          (__attribute__((address_space(3))) unsigned int*)(sA + (w * 32 + q * 8) * 64),
          16, 0, 0);
      __builtin_amdgcn_global_load_lds(
          (const __attribute__((address_space(1))) unsigned int*)gb,
          (__attribute__((address_space(3))) unsigned int*)(sB + (w * 32 + q * 8) * 64),
          16, 0, 0);
    }
    __syncthreads();

#pragma unroll
    for (int ks = 0; ks < 2; ++ks) {
      const int xo = ks ? xo1 : xo0;
      bf16x8 af[4], bf[4];
#pragma unroll
      for (int t = 0; t < 4; ++t) {
        af[t] = *(const bf16x8*)(sA + (wm + t * 16 + col) * 64 + xo);
        bf[t] = *(const bf16x8*)(sB + (wn + t * 16 + col) * 64 + xo);
      }
#pragma unroll
      for (int ti = 0; ti < 4; ++ti)
#pragma unroll
        for (int tj = 0; tj < 4; ++tj)
          acc[ti][tj] = __builtin_amdgcn_mfma_f32_16x16x32_bf16(af[ti], bf[tj], acc[ti][tj], 0, 0, 0);
    }
  }

#pragma unroll
  for (int ti = 0; ti < 4; ++ti) {
#pragma unroll
    for (int tj = 0; tj < 4; ++tj) {
      int n = bn + wn + tj * 16 + col;
      float bv_ = bias[n];
      if (z != 2) {
#pragma unroll
        for (int i = 0; i < 4; ++i) {
          int m = bm + wm + ti * 16 + quad * 4 + i;
          float v = (acc[ti][tj][i] + bv_) * pre;
          unsigned short h = f32_to_bf16_rne(v);
          float hf = __uint_as_float((unsigned)h << 16);
          Phi[(size_t)m * 1024 + n] = h;
          Plo[(size_t)m * 1024 + n] = f32_to_bf16_rne(v - hf);
        }
      } else {
        int m0 = bm + wm + ti * 16 + quad * 4;  // 4 consecutive s in one batch
        u16x4 h4, l4;
#pragma unroll
        for (int i = 0; i < 4; ++i) {
          float v = acc[ti][tj][i] + bv_;
          unsigned short h = f32_to_bf16_rne(v);
          float hf = __uint_as_float((unsigned)h << 16);
          h4[i] = h;
          l4[i] = f32_to_bf16_rne(v - hf);
        }
        size_t idx = ((size_t)((m0 >> 10) * 1024 + n)) * 1024 + (m0 & 1023);
        *(u16x4*)(Phi + idx) = h4;
        *(u16x4*)(Plo + idx) = l4;
      }
    }
  }
}

// ---------------- O-projection GEMM: 64x128 tile (512 WGs, 2/CU) ----------------

__global__ __launch_bounds__(256)
void gemm_o(const unsigned short* __restrict__ A, const unsigned short* __restrict__ Bw,
            const float* __restrict__ bias, float* __restrict__ C) {
  __shared__ unsigned short sA[64 * 64];
  __shared__ unsigned short sB[128 * 64];
  const int tid = threadIdx.x;
  const int w = tid >> 6, ln = tid & 63;
  const int bm = blockIdx.y * 64, bn = blockIdx.x * 128;
  const int wr = (w >> 1) * 32, wc = (w & 1) * 64;
  const int quad = ln >> 4, col = ln & 15;

  f32x4 acc[2][4];
  f32x4 zero = {0.0f, 0.0f, 0.0f, 0.0f};
#pragma unroll
  for (int i = 0; i < 2; ++i)
#pragma unroll
    for (int j = 0; j < 4; ++j) acc[i][j] = zero;

  const int srow = ln >> 3;
  const int gsw  = (ln & 7) ^ srow;
  const int xo0 = (quad ^ (ln & 7)) * 8;
  const int xo1 = ((quad ^ 4) ^ (ln & 7)) * 8;

  for (int k0 = 0; k0 < 1024; k0 += 64) {
    __syncthreads();
#pragma unroll
    for (int qa = 0; qa < 2; ++qa) {
      int row = w * 16 + qa * 8 + srow;
      __builtin_amdgcn_global_load_lds(
          (const __attribute__((address_space(1))) unsigned int*)(A + (size_t)(bm + row) * 1024 + k0 + gsw * 8),
          (__attribute__((address_space(3))) unsigned int*)(sA + (w * 16 + qa * 8) * 64),
          16, 0, 0);
    }
#pragma unroll
    for (int qb = 0; qb < 4; ++qb) {
      int row = w * 32 + qb * 8 + srow;
      __builtin_amdgcn_global_load_lds(
          (const __attribute__((address_space(1))) unsigned int*)(Bw + (size_t)(bn + row) * 1024 + k0 + gsw * 8),
          (__attribute__((address_space(3))) unsigned int*)(sB + (w * 32 + qb * 8) * 64),
          16, 0, 0);
    }
    __syncthreads();

#pragma unroll
    for (int ks = 0; ks < 2; ++ks) {
      const int xo = ks ? xo1 : xo0;
      bf16x8 af[2], bf[4];
#pragma unroll
      for (int t = 0; t < 2; ++t)
        af[t] = *(const bf16x8*)(sA + (wr + t * 16 + col) * 64 + xo);
#pragma unroll
      for (int t = 0; t < 4; ++t)
        bf[t] = *(const bf16x8*)(sB + (wc + t * 16 + col) * 64 + xo);
#pragma unroll
      for (int ti = 0; ti < 2; ++ti)
#pragma unroll
        for (int tj = 0; tj < 4; ++tj)
          acc[ti][tj] = __builtin_amdgcn_mfma_f32_16x16x32_bf16(af[ti], bf[tj], acc[ti][tj], 0, 0, 0);
    }
  }

#pragma unroll
  for (int ti = 0; ti < 2; ++ti) {
#pragma unroll
    for (int tj = 0; tj < 4; ++tj) {
      int n = bn + wc + tj * 16 + col;
      float bv_ = bias[n];
#pragma unroll
      for (int i = 0; i < 4; ++i) {
        int m = bm + wr + ti * 16 + quad * 4 + i;
        C[(size_t)m * 1024 + n] = acc[ti][tj][i] + bv_;
      }
    }
  }
}

// ---------------- MFMA flash attention, fused score+ctx MX quant ----------
// grid (16,64), XCD-swizzled: id=128a+8b+c -> qt=b, bh=8a+c. KT=64, 4 waves x
// 16 q-rows. LDS: K/V hi/lo 64x64 planes (8-chunk XOR swizzle, conflict-free),
// P wave-private 16x66 u32. One DPP reduction phase/tile (qdq monotonicity).

__global__ __launch_bounds__(256)
void attn_kernel(const unsigned short* __restrict__ Qhi, const unsigned short* __restrict__ Qlo,
                 const unsigned short* __restrict__ Khi, const unsigned short* __restrict__ Klo,
                 const unsigned short* __restrict__ Vthi, const unsigned short* __restrict__ Vtlo,
                 unsigned short* __restrict__ ctxq) {
  const int tid = threadIdx.x;
  const int id = blockIdx.y * 16 + blockIdx.x;
  const int qt = (id >> 3) & 15;
  const int bh = ((id >> 7) << 3) | (id & 7);
  const int b = bh >> 4, h = bh & 15;
  const int w = tid >> 6, ln = tid & 63, quad = ln >> 4, col = ln & 15;

  __shared__ __align__(16) char smem[49664];
  short* sK = (short*)smem;  // Khi@0, Klo@8192B, Vthi@16384B, Vtlo@24576B
  unsigned int* Pw = (unsigned int*)(smem + 32768) + w * 1056;  // 16 x 66 u32 per wave

  // Q fragments straight from global hi/lo planes (pre-scaled by 1/8)
  bf16x8 qh[2], ql[2];
  {
    const size_t qoff = (size_t)(b * 1024 + qt * 64 + w * 16 + col) * 1024 + h * 64 + quad * 8;
    qh[0] = *(const bf16x8*)(Qhi + qoff);
    qh[1] = *(const bf16x8*)(Qhi + qoff + 32);
    ql[0] = *(const bf16x8*)(Qlo + qoff);
    ql[1] = *(const bf16x8*)(Qlo + qoff + 32);
  }

  // staging: wave w stages plane w into region w; pointer advanced across kt
  const unsigned short* gplane = (w == 0) ? Khi : (w == 1) ? Klo : (w == 2) ? Vthi : Vtlo;
  short* splane = sK + w * 4096;
  const int r8 = ln >> 3;
  const int ch = (ln & 7) ^ r8;
  const unsigned short* bp = (w < 2)
      ? gplane + (size_t)(b * 1024 + r8) * 1024 + h * 64 + ch * 8
      : gplane + (size_t)(b * 1024 + h * 64 + r8) * 1024 + ch * 8;
  const int ktstep = (w < 2) ? 65536 : 64;

  const int xo0 = (quad ^ (col & 7)) * 8;
  const int xo1 = ((quad + 4) ^ (col & 7)) * 8;

  f32x4 o[4];
  f32x4 zero = {0.0f, 0.0f, 0.0f, 0.0f};
#pragma unroll
  for (int t = 0; t < 4; ++t) o[t] = zero;
  float m_[4], l_[4];
#pragma unroll
  for (int i = 0; i < 4; ++i) { m_[i] = -3.0e38f; l_[i] = 0.0f; }

  const float LOG2E = 1.44269504088896340736f;

#pragma unroll 1
  for (int kt = 0; kt < 16; ++kt) {
    __syncthreads();  // prior tile's fragment reads complete before restaging
#pragma unroll
    for (int g = 0; g < 8; ++g) {
      __builtin_amdgcn_global_load_lds(
          (const __attribute__((address_space(1))) unsigned int*)(bp + g * 8192),
          (__attribute__((address_space(3))) unsigned int*)(splane + g * 512),
          16, 0, 0);
    }
    bp += ktstep;
    __syncthreads();  // staging visible

    // S = (Qhi+Qlo)·(Khi+Klo)^T, 3 cross terms (Q pre-scaled by 1/8)
    f32x4 s[4];
#pragma unroll
    for (int t = 0; t < 4; ++t) s[t] = zero;
#pragma unroll
    for (int t = 0; t < 4; ++t) {
      const int rb = (t * 16 + col) * 64;
#pragma unroll
      for (int ks = 0; ks < 2; ++ks) {
        const int xo = ks ? xo1 : xo0;
        bf16x8 kh = *(const bf16x8*)(sK +        rb + xo);
        bf16x8 kl = *(const bf16x8*)(sK + 4096 + rb + xo);
        s[t] = __builtin_amdgcn_mfma_f32_16x16x32_bf16(ql[ks], kh, s[t], 0, 0, 0);
        s[t] = __builtin_amdgcn_mfma_f32_16x16x32_bf16(qh[ks], kl, s[t], 0, 0, 0);
        s[t] = __builtin_amdgcn_mfma_f32_16x16x32_bf16(qh[ks], kh, s[t], 0, 0, 0);
      }
    }

    // ---- MX quantize scores, ONE reduction phase ----
    // blocks: frags (0,1) and (2,3). Reduce signed max+min per block (DPP);
    // amax = max(smax,-smin); row-max of quantized = dq(qdq(smax)) (monotone).
    float sm0[4], sn0[4], sm1[4], sn1[4];
#pragma unroll
    for (int i = 0; i < 4; ++i) {
      sm0[i] = dpp_max16(fmaxf(s[0][i], s[1][i]));
      sn0[i] = dpp_min16(fminf(s[0][i], s[1][i]));
      sm1[i] = dpp_max16(fmaxf(s[2][i], s[3][i]));
      sn1[i] = dpp_min16(fminf(s[2][i], s[3][i]));
    }
    float mt[4];
#pragma unroll
    for (int i = 0; i < 4; ++i) {
      float sc0, iv0, sc1, iv1;
      mx_scale_bits(fmaxf(sm0[i], -sn0[i]), sc0, iv0);
      mx_scale_bits(fmaxf(sm1[i], -sn1[i]), sc1, iv1);
      float scl0 = sc0 * LOG2E, scl1 = sc1 * LOG2E;  // fold dequant + log2e
      float q0 = s[0][i] * iv0, q1 = s[1][i] * iv0;
      float q2 = s[2][i] * iv1, q3 = s[3][i] * iv1;
      qdq2(q0, q1);
      qdq2(q2, q3);
      s[0][i] = q0 * scl0; s[1][i] = q1 * scl0;
      s[2][i] = q2 * scl1; s[3][i] = q3 * scl1;
      float d0 = sm0[i] * iv0, d1 = sm1[i] * iv1;
      qdq2(d0, d1);
      mt[i] = fmaxf(d0 * scl0, d1 * scl1);
    }

    // online softmax (log2 domain)
#pragma unroll
    for (int i = 0; i < 4; ++i) {
      float mnew  = fmaxf(m_[i], mt[i]);
      float alpha = __builtin_amdgcn_exp2f(m_[i] - mnew);
      m_[i] = mnew;
      l_[i] *= alpha;
#pragma unroll
      for (int t = 0; t < 4; ++t) o[t][i] *= alpha;
#pragma unroll
      for (int t = 0; t < 4; ++t) {
        float p = __builtin_amdgcn_exp2f(s[t][i] - mnew);
        s[t][i] = p;
        l_[i] += p;
      }
    }

    // P: C-layout -> wave-private LDS (hi|lo packed u32, stride 66) -> A-frags
#pragma unroll
    for (int i = 0; i < 4; ++i) {
      const int prow = (quad * 4 + i) * 66;
#pragma unroll
      for (int pp = 0; pp < 2; ++pp) {
        float a = s[pp * 2 + 0][i], c = s[pp * 2 + 1][i];
        __hip_bfloat162 h2 = __float22bfloat162_rn(make_float2(a, c));
        unsigned uh = *(unsigned*)&h2;               // lo16=bf(a), hi16=bf(c)
        float af = __uint_as_float(uh << 16);
        float cf = __uint_as_float(uh & 0xffff0000u);
        __hip_bfloat162 l2 = __float22bfloat162_rn(make_float2(a - af, c - cf));
        unsigned ul = *(unsigned*)&l2;
        Pw[prow + pp * 32 + col]      = (uh << 16) | (ul & 0xffffu);
        Pw[prow + pp * 32 + 16 + col] = (uh & 0xffff0000u) | (ul >> 16);
      }
    }
    bf16x8 pah[2], pal[2];
#pragma unroll
    for (int ks = 0; ks < 2; ++ks) {
      const unsigned int* pr = Pw + col * 66 + ks * 32 + quad * 8;
      uint4 u0 = *(const uint4*)pr;
      uint4 u1 = *(const uint4*)(pr + 4);
      unsigned int uu[8] = {u0.x, u0.y, u0.z, u0.w, u1.x, u1.y, u1.z, u1.w};
      bf16x8 hh, llv;
#pragma unroll
      for (int e = 0; e < 8; ++e) {
        hh[e]  = (short)(uu[e] >> 16);
        llv[e] = (short)(uu[e] & 0xffffu);
      }
      pah[ks] = hh; pal[ks] = llv;
    }

    // O += (Phi+Plo)·(Vhi+Vlo), 3 cross terms
#pragma unroll
    for (int nt = 0; nt < 4; ++nt) {
      const int rb = (nt * 16 + col) * 64;
#pragma unroll
      for (int ks = 0; ks < 2; ++ks) {
        const int xo = ks ? xo1 : xo0;
        bf16x8 vh = *(const bf16x8*)(sK +  8192 + rb + xo);
        bf16x8 vl = *(const bf16x8*)(sK + 12288 + rb + xo);
        o[nt] = __builtin_amdgcn_mfma_f32_16x16x32_bf16(pal[ks], vh, o[nt], 0, 0, 0);
        o[nt] = __builtin_amdgcn_mfma_f32_16x16x32_bf16(pah[ks], vl, o[nt], 0, 0, 0);
        o[nt] = __builtin_amdgcn_mfma_f32_16x16x32_bf16(pah[ks], vh, o[nt], 0, 0, 0);
      }
    }
  }

  // normalize + fused ctx MX quant (blocks of 32 along E = frag pairs) -> bf16
  float cam0[4], cam1[4];
#pragma unroll
  for (int i = 0; i < 4; ++i) {
    float invl = 1.0f / dpp_sum16(l_[i]);
#pragma unroll
    for (int t = 0; t < 4; ++t) o[t][i] *= invl;
    cam0[i] = dpp_max16(fmaxf(__builtin_fabsf(o[0][i]), __builtin_fabsf(o[1][i])));
    cam1[i] = dpp_max16(fmaxf(__builtin_fabsf(o[2][i]), __builtin_fabsf(o[3][i])));
  }
#pragma unroll
  for (int i = 0; i < 4; ++i) {
    float sc0, iv0, sc1, iv1;
    mx_scale_bits(cam0[i], sc0, iv0);
    mx_scale_bits(cam1[i], sc1, iv1);
    float q0 = o[0][i] * iv0, q1 = o[1][i] * iv0;
    float q2 = o[2][i] * iv1, q3 = o[3][i] * iv1;
    qdq2(q0, q1);
    qdq2(q2, q3);
    q0 *= sc0; q1 *= sc0; q2 *= sc1; q3 *= sc1;
    int rowg = b * 1024 + qt * 64 + w * 16 + quad * 4 + i;
    size_t base = (size_t)rowg * 1024 + h * 64 + col;
    ctxq[base +  0] = (unsigned short)(__float_as_uint(q0) >> 16);
    ctxq[base + 16] = (unsigned short)(__float_as_uint(q1) >> 16);
    ctxq[base + 32] = (unsigned short)(__float_as_uint(q2) >> 16);
    ctxq[base + 48] = (unsigned short)(__float_as_uint(q3) >> 16);
  }
}

// ---------------- launch ----------------

extern "C" void kernel_launch(void* const* d_in, const int* in_sizes, int n_in,
                              void* d_out, int out_size, void* d_ws, size_t ws_size,
                              hipStream_t stream) {
  (void)in_sizes; (void)n_in; (void)out_size; (void)ws_size;
  const float* x  = (const float*)d_in[0];
  const float* Wq = (const float*)d_in[1];
  const float* bq = (const float*)d_in[2];
  const float* Wk = (const float*)d_in[3];
  const float* bk = (const float*)d_in[4];
  const float* Wv = (const float*)d_in[5];
  const float* bv = (const float*)d_in[6];
  const float* Wo = (const float*)d_in[7];
  const float* bo = (const float*)d_in[8];

  char* wsb = (char*)d_ws;
  const size_t MB = (size_t)1 << 20;
  unsigned short* XQb   = (unsigned short*)(wsb + 0);
  unsigned short* WQb   = (unsigned short*)(wsb + 8 * MB);
  unsigned short* WKb   = (unsigned short*)(wsb + 10 * MB);
  unsigned short* WVb   = (unsigned short*)(wsb + 12 * MB);
  unsigned short* WOb   = (unsigned short*)(wsb + 14 * MB);
  unsigned short* Qhi   = (unsigned short*)(wsb + 16 * MB);
  unsigned short* Qlo   = (unsigned short*)(wsb + 24 * MB);
  unsigned short* Khi   = (unsigned short*)(wsb + 32 * MB);
  unsigned short* Klo   = (unsigned short*)(wsb + 40 * MB);
  unsigned short* Vthi  = (unsigned short*)(wsb + 48 * MB);
  unsigned short* Vtlo  = (unsigned short*)(wsb + 56 * MB);
  unsigned short* CTXQb = XQb;  // reuse: XQ dead after V projection

  mxq_all<<<1024, 256, 0, stream>>>(x, Wq, Wk, Wv, Wo, XQb, WQb, WKb, WVb, WOb);

  dim3 qkvgrid(E_DIM / 128, NROWS / 128, 3);  // (8, 32, 3) = 768 WGs
  gemm_qkv<<<qkvgrid, 256, 0, stream>>>(XQb, WQb, WKb, WVb, bq, bk, bv,
                                        Qhi, Qlo, Khi, Klo, Vthi, Vtlo);

  dim3 agrid(16, 64);  // 1024 WGs, XCD-swizzled inside the kernel
  attn_kernel<<<agrid, 256, 0, stream>>>(Qhi, Qlo, Khi, Klo, Vthi, Vtlo, CTXQb);

  dim3 ogrid(E_DIM / 128, NROWS / 64);  // (8, 64) = 512 WGs
  gemm_o<<<ogrid, 256, 0, stream>>>(CTXQb, WOb, bo, (float*)d_out);
}